// Round 7
// baseline (114.784 us; speedup 1.0000x reference)
//
#include <hip/hip_runtime.h>

typedef _Float16 f16;
typedef _Float16 f16x4 __attribute__((ext_vector_type(4)));
typedef _Float16 f16x8 __attribute__((ext_vector_type(8)));
typedef float    f32x4 __attribute__((ext_vector_type(4)));

#define NB 32
#define ND 256
#define NT 1024
#define MAGIC64 0x5A5A3C3CA5A5C3C3ull

// ---------------------------------------------------------------------------
// Kernel 1: W fragment prep (tiny, ~1.5 us).
// wf[ks8(8)][nt(16)][lane(64)][j(8)],
//   value = Wm[n = nt*16+(lane&15)][k = ks8*32+(lane>>4)*8+j], diag=0.
// ---------------------------------------------------------------------------
__global__ __launch_bounds__(256) void wprep_kernel(
    const float* __restrict__ W, f16* __restrict__ wf)
{
    const int gid  = blockIdx.x * 256 + threadIdx.x;   // 0..8191
    const int ks8  = gid >> 10;
    const int nt   = (gid >> 6) & 15;
    const int lane = gid & 63;
    const int nrow = nt * 16 + (lane & 15);
    const int k0   = ks8 * 32 + (lane >> 4) * 8;
    f16x8 v;
    #pragma unroll
    for (int j = 0; j < 8; ++j) {
        int k = k0 + j;
        float w = W[nrow * 256 + k];
        v[j] = (f16)((k == nrow) ? 0.0f : w);
    }
    *reinterpret_cast<f16x8*>(wf + (size_t)gid * 8) = v;
}

// ---------------------------------------------------------------------------
// Kernel 2: fused IIR + bilinear, 512 blocks x 512 threads, 34 KB LDS,
// <=128 VGPR -> 2 blocks/CU, all 512 blocks co-resident (flag spin safe).
//
// Phase 1: block g IIR-scans rows [16g, 16g+16) (wave w: rows 16g+2w(+1),
//   second row prefetched). k[u] = om*(d^u - m^u) => y = om*(S_d - S_m),
//   S_a[t] = x[t] + a*S_a[t-1]. Lane l owns t [16l,16l+16): local scan +
//   weighted Kogge-Stone carry + reconstruct.
// Release: flags[g] = MAGIC64 (agent-scope release). Idempotent across graph
//   replays: stale MAGIC short-cuts the spin, but y16 bytes are identical
//   every replay, so consumers read correct data regardless.
// Phase 2 (b = g>>4, tt = g&15): spin-acquire the 16 cohort flags of batch b
//   (cohort is CLOSED: batch b's consumers == batch b's producers, so y16
//   handoff stays in L2/L3). Then bilinear (R6-verified body):
//   out[b,t] = sum_n y[n,t]*(z[n,t]+1) - 70, z = Wm*y. 8 waves; wave w owns
//   n-range [32w,32w+32), 64 t. A-frags straight from global wf (L2). Y tile
//   32 KB LDS, transposed [t][m], XOR swizzle (u16 idx ^= (t&7)<<3).
// ---------------------------------------------------------------------------
__global__ __launch_bounds__(512, 4) void dbnn_fused_kernel(
    const float* __restrict__ x, const float* __restrict__ tau_rise,
    const float* __restrict__ tau_decay, const float* __restrict__ omega,
    const f16* __restrict__ wf, f16* __restrict__ y16,
    unsigned long long* __restrict__ flags, float* __restrict__ out)
{
    __shared__ __align__(16) f16 Yl[16384];    // 32 KB (64 t x 256 m)
    __shared__ float sbuf[8][64];              // 2 KB cross-wave partials

    const int tid  = threadIdx.x;
    const int lane = tid & 63;
    const int w    = tid >> 6;
    const int g    = blockIdx.x;

    // ---------------- phase 1: IIR scan, 2 rows per wave ------------------
    {
        const int r0 = g * 16 + w * 2;
        const float* xp = x + (size_t)r0 * NT + lane * 16;

        f32x4 pre[4];
        #pragma unroll
        for (int i = 0; i < 4; ++i) pre[i] = *(const f32x4*)(xp + i * 4);

        #pragma unroll
        for (int rr = 0; rr < 2; ++rr) {
            float xv[16];
            #pragma unroll
            for (int i = 0; i < 4; ++i) {
                xv[i*4+0] = pre[i][0]; xv[i*4+1] = pre[i][1];
                xv[i*4+2] = pre[i][2]; xv[i*4+3] = pre[i][3];
            }
            if (rr == 0) {  // prefetch row 2 while scanning row 1
                #pragma unroll
                for (int i = 0; i < 4; ++i)
                    pre[i] = *(const f32x4*)(xp + NT + i * 4);
            }

            const int row = r0 + rr;
            const int n   = row & (ND - 1);
            const float ad = expf(-1.0f / tau_decay[n]);
            const float am = expf(-(1.0f / tau_rise[n] + 1.0f / tau_decay[n]));
            const float om = omega[n];

            // local (carry-free) inclusive scans, both states
            float ld[16], lm[16];
            float sd = 0.f, sm = 0.f;
            #pragma unroll
            for (int i = 0; i < 16; ++i) {
                sd = fmaf(ad, sd, xv[i]); ld[i] = sd;
                sm = fmaf(am, sm, xv[i]); lm[i] = sm;
            }

            // a^16 ladders
            float t2;
            t2 = ad*ad; t2 = t2*t2; t2 = t2*t2; float wd = t2*t2;
            t2 = am*am; t2 = t2*t2; t2 = t2*t2; float wm = t2*t2;

            // weighted Kogge-Stone across lanes
            float Xd = sd, Xm = sm;
            #pragma unroll
            for (int off = 1; off < 64; off <<= 1) {
                float pd = __shfl_up(Xd, off);
                float pm = __shfl_up(Xm, off);
                if (lane >= off) { Xd = fmaf(wd, pd, Xd); Xm = fmaf(wm, pm, Xm); }
                wd *= wd; wm *= wm;
            }
            float cd = __shfl_up(Xd, 1);
            float cm = __shfl_up(Xm, 1);
            if (lane == 0) { cd = 0.f; cm = 0.f; }

            // reconstruct: S[16l+i] = local_i + a^(i+1) * carry
            f16x8 o0, o1;
            float qd = ad, qm = am;
            #pragma unroll
            for (int i = 0; i < 16; ++i) {
                float yv = om * (fmaf(qd, cd, ld[i]) - fmaf(qm, cm, lm[i]));
                if (i < 8) o0[i] = (f16)yv; else o1[i - 8] = (f16)yv;
                qd *= ad; qm *= am;
            }
            f16* dst = y16 + (size_t)row * NT + lane * 16;
            *reinterpret_cast<f16x8*>(dst)     = o0;
            *reinterpret_cast<f16x8*>(dst + 8) = o1;
        }
    }

    // ---------------- release own flag, acquire cohort --------------------
    __syncthreads();                 // all waves' y16 stores issued
    if (tid == 0) {
        __threadfence();
        __hip_atomic_store(&flags[g], MAGIC64,
                           __ATOMIC_RELEASE, __HIP_MEMORY_SCOPE_AGENT);
    }

    const int tt = g & 15;
    const int b  = g >> 4;
    const int t0 = tt * 64;

    if (tid == 0) {
        const int base = b << 4;
        #pragma unroll 1
        for (int p = 0; p < 16; ++p) {
            while (__hip_atomic_load(&flags[base + p], __ATOMIC_ACQUIRE,
                                     __HIP_MEMORY_SCOPE_AGENT) != MAGIC64)
                __builtin_amdgcn_s_sleep(4);
        }
    }
    __syncthreads();

    // ---------------- phase 2: bilinear (R6-verified body) ----------------
    // stage Y tile: thread (m, t-half of 32) streams row m's window
    {
        const int m    = tid & 255;
        const int half = tid >> 8;
        const f16* ysrc = y16 + ((size_t)(b * ND + m)) * NT + t0 + half * 32;
        f16x8 vy[4];
        #pragma unroll
        for (int c = 0; c < 4; ++c)
            vy[c] = *reinterpret_cast<const f16x8*>(ysrc + c * 8);
        #pragma unroll
        for (int c = 0; c < 4; ++c) {
            #pragma unroll
            for (int e = 0; e < 8; ++e) {
                int tl = half * 32 + c * 8 + e;     // tl&7 == e
                Yl[tl * 256 + (m ^ (e << 3))] = vy[c][e];
            }
        }
    }
    __syncthreads();

    const int gq = lane >> 4;

    int tl4[4], sw4[4];
    #pragma unroll
    for (int tf = 0; tf < 4; ++tf) {
        tl4[tf] = tf * 16 + (lane & 15);
        sw4[tf] = (tl4[tf] & 7) << 3;
    }

    f32x4 acc[2][4];                    // [a: n-frag][tf]
    #pragma unroll
    for (int a = 0; a < 2; ++a)
        #pragma unroll
        for (int tf = 0; tf < 4; ++tf) acc[a][tf] = (f32x4){0.f,0.f,0.f,0.f};

    #pragma unroll
    for (int ks = 0; ks < 8; ++ks) {
        // A-frags straight from global (L2): nt = 2w+a
        f16x8 afrag[2];
        #pragma unroll
        for (int a = 0; a < 2; ++a)
            afrag[a] = *reinterpret_cast<const f16x8*>(
                &wf[(size_t)(((ks * 16) + (2 * w + a)) * 64 + lane) * 8]);
        f16x8 bfrag[4];
        #pragma unroll
        for (int tf = 0; tf < 4; ++tf) {
            int m0 = ks * 32 + gq * 8;
            bfrag[tf] = *reinterpret_cast<const f16x8*>(
                &Yl[tl4[tf] * 256 + (m0 ^ sw4[tf])]);
        }
        #pragma unroll
        for (int a = 0; a < 2; ++a)
            #pragma unroll
            for (int tf = 0; tf < 4; ++tf)
                acc[a][tf] = __builtin_amdgcn_mfma_f32_16x16x32_f16(
                    afrag[a], bfrag[tf], acc[a][tf], 0, 0, 0);
    }

    // epilogue: per t-col partial = sum over this wave's 32 n of y*(z+1)
    #pragma unroll
    for (int tf = 0; tf < 4; ++tf) {
        float p = 0.f;
        #pragma unroll
        for (int a = 0; a < 2; ++a) {
            int n0 = w * 32 + a * 16 + gq * 4;
            f16x4 yv4 = *reinterpret_cast<const f16x4*>(
                &Yl[tl4[tf] * 256 + (n0 ^ sw4[tf])]);
            #pragma unroll
            for (int r = 0; r < 4; ++r)
                p = fmaf((float)yv4[r], acc[a][tf][r] + 1.0f, p);
        }
        p += __shfl_xor(p, 16);
        p += __shfl_xor(p, 32);
        if (lane < 16) sbuf[w][tf * 16 + lane] = p;
    }
    __syncthreads();
    if (tid < 64) {
        float s = sbuf[0][tid] + sbuf[1][tid] + sbuf[2][tid] + sbuf[3][tid]
                + sbuf[4][tid] + sbuf[5][tid] + sbuf[6][tid] + sbuf[7][tid];
        out[b * NT + t0 + tid] = s - 70.0f;
    }
}

// ---------------------------------------------------------------------------
extern "C" void kernel_launch(void* const* d_in, const int* in_sizes, int n_in,
                              void* d_out, int out_size, void* d_ws, size_t ws_size,
                              hipStream_t stream) {
    const float* x         = (const float*)d_in[0];
    const float* tau_rise  = (const float*)d_in[1];
    const float* tau_decay = (const float*)d_in[2];
    const float* omega     = (const float*)d_in[3];
    const float* W         = (const float*)d_in[4];
    float* out = (float*)d_out;

    f16* y16 = (f16*)d_ws;                                          // 16 MB
    f16* wfr = (f16*)((char*)d_ws + (size_t)16 * 1024 * 1024);      // 128 KB
    unsigned long long* flags =
        (unsigned long long*)((char*)d_ws + (size_t)17 * 1024 * 1024); // 4 KB

    wprep_kernel<<<32, 256, 0, stream>>>(W, wfr);
    dbnn_fused_kernel<<<512, 512, 0, stream>>>(
        x, tau_rise, tau_decay, omega, wfr, y16, flags, out);
}

// Round 8
// 24.372 us; speedup vs baseline: 4.7097x; 4.7097x over previous
//
#include <hip/hip_runtime.h>

typedef _Float16 f16;
typedef _Float16 f16x4 __attribute__((ext_vector_type(4)));
typedef _Float16 f16x8 __attribute__((ext_vector_type(8)));
typedef float    f32x4 __attribute__((ext_vector_type(4)));

#define NB 32
#define ND 256
#define NT 1024

// ---------------------------------------------------------------------------
// Kernel 1: blocks [0,2048) = IIR checkpoint scan; blocks >=2048 = W prep.
//
// Checkpoint scan: one wave per (b,n) row; lane l owns t in [16l,16l+16).
// Only the running states are needed (no per-element locals, no y store):
// local 16-step fold -> weighted Kogge-Stone across lanes -> odd lane 2c-1
// holds S at t = 32c-1. chk[row][c] = (S_d, S_m) at end of t=32c-1 (c=0 -> 0).
// Traffic: 32 MB read + 2 MB write (vs 48 MB in the y16-materializing version).
//
// W prep layout: wf[ks8(8)][nt(16)][lane(64)][j(8)],
//   value = Wm[n = nt*16+(lane&15)][k = ks8*32+(lane>>4)*8+j], diag=0.
// ---------------------------------------------------------------------------
__global__ __launch_bounds__(256) void scan_chk_wprep_kernel(
    const float* __restrict__ x, const float* __restrict__ tau_rise,
    const float* __restrict__ tau_decay, const float* __restrict__ omega,
    const float* __restrict__ W, float2* __restrict__ chk,
    f16* __restrict__ wf)
{
    if (blockIdx.x >= 2048) {
        const int gid  = (blockIdx.x - 2048) * 256 + threadIdx.x;  // 0..8191
        const int ks8  = gid >> 10;
        const int nt   = (gid >> 6) & 15;
        const int lane = gid & 63;
        const int nrow = nt * 16 + (lane & 15);
        const int k0   = ks8 * 32 + (lane >> 4) * 8;
        f16x8 v;
        #pragma unroll
        for (int j = 0; j < 8; ++j) {
            int k = k0 + j;
            float w = W[nrow * 256 + k];
            v[j] = (f16)((k == nrow) ? 0.0f : w);
        }
        *reinterpret_cast<f16x8*>(wf + (size_t)gid * 8) = v;
        return;
    }

    const int lane = threadIdx.x & 63;
    const int wid  = threadIdx.x >> 6;
    const int row  = blockIdx.x * 4 + wid;      // b*ND + n
    const int n    = row & (ND - 1);

    const float ad = expf(-1.0f / tau_decay[n]);
    const float am = expf(-(1.0f / tau_rise[n] + 1.0f / tau_decay[n]));

    const float* xr = x + (size_t)row * NT + lane * 16;
    f32x4 v0 = *reinterpret_cast<const f32x4*>(xr);
    f32x4 v1 = *reinterpret_cast<const f32x4*>(xr + 4);
    f32x4 v2 = *reinterpret_cast<const f32x4*>(xr + 8);
    f32x4 v3 = *reinterpret_cast<const f32x4*>(xr + 12);

    // local 16-step fold (no per-element locals needed)
    float sd = 0.f, sm = 0.f;
    #pragma unroll
    for (int i = 0; i < 4; ++i) { sd = fmaf(ad, sd, v0[i]); sm = fmaf(am, sm, v0[i]); }
    #pragma unroll
    for (int i = 0; i < 4; ++i) { sd = fmaf(ad, sd, v1[i]); sm = fmaf(am, sm, v1[i]); }
    #pragma unroll
    for (int i = 0; i < 4; ++i) { sd = fmaf(ad, sd, v2[i]); sm = fmaf(am, sm, v2[i]); }
    #pragma unroll
    for (int i = 0; i < 4; ++i) { sd = fmaf(ad, sd, v3[i]); sm = fmaf(am, sm, v3[i]); }

    // a^16 ladders
    float t2;
    t2 = ad * ad; t2 = t2 * t2; t2 = t2 * t2; float wd = t2 * t2;
    t2 = am * am; t2 = t2 * t2; t2 = t2 * t2; float wm = t2 * t2;

    // weighted Kogge-Stone: X_l = inclusive state at t = 16(l+1)-1
    float Xd = sd, Xm = sm;
    #pragma unroll
    for (int off = 1; off < 64; off <<= 1) {
        float pd = __shfl_up(Xd, off);
        float pm = __shfl_up(Xm, off);
        if (lane >= off) { Xd = fmaf(wd, pd, Xd); Xm = fmaf(wm, pm, Xm); }
        wd *= wd; wm *= wm;
    }

    // store checkpoints: c-th = state entering t = 32c
    float2* cr = chk + (size_t)row * 32;
    if (lane == 0) cr[0] = make_float2(0.f, 0.f);
    if ((lane & 1) && lane < 63) cr[(lane + 1) >> 1] = make_float2(Xd, Xm);
}

// ---------------------------------------------------------------------------
// Kernel 2: recompute y tile in-block from x (L2/L3-warm) + checkpoint, then
// bilinear: out[b,t] = sum_n y[n,t]*(z[n,t]+1) - 70,  z = Wm*y.
// Block = (b, t-tile of 64), 512 threads = 8 waves.
// Recompute: thread (m = tid>>1, h = tid&1) runs the 2-state IIR for 32 steps
//   from chk[b*ND+m][tt*2+h], writing y straight into Yl (transposed [t][m],
//   XOR swizzle u16 idx ^= (t&7)<<3). y never touches HBM.
// MFMA: wave w owns n-range [32w,32w+32), all 64 t; A-frags straight from
//   global wf (L2-resident). Cross-wave n-reduction via sbuf.
// ---------------------------------------------------------------------------
__global__ __launch_bounds__(512, 4) void bilinear_kernel(
    const float* __restrict__ x, const float* __restrict__ tau_rise,
    const float* __restrict__ tau_decay, const float* __restrict__ omega,
    const float2* __restrict__ chk, const f16* __restrict__ wf,
    float* __restrict__ out)
{
    __shared__ __align__(16) f16 Yl[16384];    // 32 KB (64 t x 256 m)
    __shared__ float sbuf[8][64];              // 2 KB cross-wave partials

    const int bi = blockIdx.x;
    const int tt = bi & 15;
    const int b  = bi >> 4;
    const int t0 = tt * 64;
    const int tid = threadIdx.x;

    // ---- recompute y tile from x + checkpoint ----
    {
        const int m = tid >> 1;            // row n within batch
        const int h = tid & 1;             // t-half of 32
        const int rowg = b * ND + m;
        const float ad = expf(-1.0f / tau_decay[m]);
        const float am = expf(-(1.0f / tau_rise[m] + 1.0f / tau_decay[m]));
        const float om = omega[m];

        const float* xs = x + (size_t)rowg * NT + t0 + h * 32;
        f32x4 xv[8];
        #pragma unroll
        for (int c = 0; c < 8; ++c)
            xv[c] = *reinterpret_cast<const f32x4*>(xs + c * 4);

        float2 ck = chk[(size_t)rowg * 32 + tt * 2 + h];
        float Sd = ck.x, Sm = ck.y;
        #pragma unroll
        for (int i = 0; i < 32; ++i) {
            float xi = xv[i >> 2][i & 3];
            Sd = fmaf(ad, Sd, xi);
            Sm = fmaf(am, Sm, xi);
            float yv = om * (Sd - Sm);
            int tl = h * 32 + i;
            Yl[tl * 256 + (m ^ ((tl & 7) << 3))] = (f16)yv;
        }
    }
    __syncthreads();

    const int lane = tid & 63;
    const int w    = tid >> 6;          // wave: n-range [32w, 32w+32)
    const int gq   = lane >> 4;

    int tl4[4], sw4[4];
    #pragma unroll
    for (int tf = 0; tf < 4; ++tf) {
        tl4[tf] = tf * 16 + (lane & 15);
        sw4[tf] = (tl4[tf] & 7) << 3;
    }

    f32x4 acc[2][4];                    // [a: n-frag][tf]
    #pragma unroll
    for (int a = 0; a < 2; ++a)
        #pragma unroll
        for (int tf = 0; tf < 4; ++tf) acc[a][tf] = (f32x4){0.f,0.f,0.f,0.f};

    #pragma unroll
    for (int ks = 0; ks < 8; ++ks) {
        // A-frags straight from global (L2): nt = 2w+a
        f16x8 afrag[2];
        #pragma unroll
        for (int a = 0; a < 2; ++a)
            afrag[a] = *reinterpret_cast<const f16x8*>(
                &wf[(size_t)(((ks * 16) + (2 * w + a)) * 64 + lane) * 8]);
        f16x8 bfrag[4];
        #pragma unroll
        for (int tf = 0; tf < 4; ++tf) {
            int m0 = ks * 32 + gq * 8;
            bfrag[tf] = *reinterpret_cast<const f16x8*>(
                &Yl[tl4[tf] * 256 + (m0 ^ sw4[tf])]);
        }
        #pragma unroll
        for (int a = 0; a < 2; ++a)
            #pragma unroll
            for (int tf = 0; tf < 4; ++tf)
                acc[a][tf] = __builtin_amdgcn_mfma_f32_16x16x32_f16(
                    afrag[a], bfrag[tf], acc[a][tf], 0, 0, 0);
    }

    // epilogue: per t-col partial = sum over this wave's 32 n of y*(z+1)
    #pragma unroll
    for (int tf = 0; tf < 4; ++tf) {
        float p = 0.f;
        #pragma unroll
        for (int a = 0; a < 2; ++a) {
            int n0 = w * 32 + a * 16 + gq * 4;
            f16x4 yv4 = *reinterpret_cast<const f16x4*>(
                &Yl[tl4[tf] * 256 + (n0 ^ sw4[tf])]);
            #pragma unroll
            for (int r = 0; r < 4; ++r)
                p = fmaf((float)yv4[r], acc[a][tf][r] + 1.0f, p);
        }
        p += __shfl_xor(p, 16);
        p += __shfl_xor(p, 32);
        if (lane < 16) sbuf[w][tf * 16 + lane] = p;
    }
    __syncthreads();
    if (tid < 64) {
        float s = sbuf[0][tid] + sbuf[1][tid] + sbuf[2][tid] + sbuf[3][tid]
                + sbuf[4][tid] + sbuf[5][tid] + sbuf[6][tid] + sbuf[7][tid];
        out[b * NT + t0 + tid] = s - 70.0f;
    }
}

// ---------------------------------------------------------------------------
extern "C" void kernel_launch(void* const* d_in, const int* in_sizes, int n_in,
                              void* d_out, int out_size, void* d_ws, size_t ws_size,
                              hipStream_t stream) {
    const float* x         = (const float*)d_in[0];
    const float* tau_rise  = (const float*)d_in[1];
    const float* tau_decay = (const float*)d_in[2];
    const float* omega     = (const float*)d_in[3];
    const float* W         = (const float*)d_in[4];
    float* out = (float*)d_out;

    float2* chk = (float2*)d_ws;                                   // 2 MB
    f16*    wfr = (f16*)((char*)d_ws + (size_t)4 * 1024 * 1024);   // 128 KB

    scan_chk_wprep_kernel<<<2048 + 32, 256, 0, stream>>>(
        x, tau_rise, tau_decay, omega, W, chk, wfr);
    bilinear_kernel<<<NB * 16, 512, 0, stream>>>(
        x, tau_rise, tau_decay, omega, chk, wfr, out);
}